// Round 8
// baseline (212.578 us; speedup 1.0000x reference)
//
#include <hip/hip_runtime.h>

#define NSEQ 2048
#define KDIM 1024
#define DH   64
#define NS   8
#define NR   2

typedef short bf16x8 __attribute__((ext_vector_type(8)));
typedef float f32x4  __attribute__((ext_vector_type(4)));

typedef unsigned short ushort_ma __attribute__((may_alias));
typedef bf16x8         bf16x8_ma __attribute__((may_alias));
typedef uint4          uint4_ma  __attribute__((may_alias));
typedef uint2          uint2_ma  __attribute__((may_alias));
typedef float4         float4_ma __attribute__((may_alias));

__device__ __forceinline__ unsigned short f2bf(float f) {
    unsigned int u = __builtin_bit_cast(unsigned int, f);
    u = (u + 0x7FFFu + ((u >> 16) & 1u)) >> 16;   // RTN-even
    return (unsigned short)u;
}
__device__ __forceinline__ float bf2f(unsigned short h) {
    unsigned int u = ((unsigned int)h) << 16;
    return __builtin_bit_cast(float, u);
}
__device__ __forceinline__ unsigned int cvt_pk_bf16(float lo, float hi) {
    unsigned int r;
    asm("v_cvt_pk_bf16_f32 %0, %1, %2" : "=v"(r) : "v"(lo), "v"(hi));
    return r;
}
// LDS-only barrier: ds_writes visible, but global reg-loads stay IN FLIGHT (T4).
#define BAR() do { asm volatile("s_waitcnt lgkmcnt(0)" ::: "memory"); \
                   __builtin_amdgcn_s_barrier(); } while (0)

// ============ prep 1: weight transpose + f32->bf16 ============
__global__ __launch_bounds__(256) void prep_w_k(
    const float* __restrict__ Wsq, const float* __restrict__ Wsk,
    const float* __restrict__ Wrq, const float* __restrict__ Wrv,
    const float* __restrict__ Wout,
    unsigned short* __restrict__ Wt, unsigned short* __restrict__ Wot)
{
    __shared__ float sT[64][65];
    const int tid = threadIdx.x;
    const int bid = blockIdx.x;

    const float* src; int ldw, k0, n0, scol, ldo;
    unsigned short* dst;
    float sc = 1.0f;
    if (bid < 416) {
        int kt = bid / 26, nt = bid % 26;
        k0 = kt * 64; n0 = nt * 64;
        if (n0 >= 1024 && n0 < 1536) return;
        if (n0 < 512)       { src = Wsq; ldw = 512; scol = n0;        sc = 0.125f * 1.44269504089f; }
        else if (n0 < 1024) { src = Wsk; ldw = 512; scol = n0 - 512;  }
        else                { src = Wrv; ldw = 128; scol = n0 - 1536; }
        dst = Wt; ldo = KDIM;
    } else {
        int r = bid - 416;
        int kt = r >> 4, nt = r & 15;
        k0 = kt * 64; n0 = nt * 64; scol = n0;
        src = Wout; ldw = KDIM;
        dst = Wot; ldo = 512;
    }

#pragma unroll
    for (int p = 0; p < 4; ++p) {
        int row = (tid >> 4) + p * 16;
        int col = (tid & 15) * 4;
        float4 v = *(const float4*)&src[(size_t)(k0 + row) * ldw + scol + col];
        sT[row][col + 0] = v.x; sT[row][col + 1] = v.y;
        sT[row][col + 2] = v.z; sT[row][col + 3] = v.w;
    }
    __syncthreads();

    {
        int n_l = tid >> 2, kg = (tid & 3) * 16;
        unsigned int w[8];
#pragma unroll
        for (int j = 0; j < 8; ++j) {
            unsigned short a = f2bf(sT[kg + 2 * j][n_l] * sc);
            unsigned short b = f2bf(sT[kg + 2 * j + 1][n_l] * sc);
            w[j] = (unsigned)a | ((unsigned)b << 16);
        }
        unsigned short* o = dst + (size_t)(n0 + n_l) * ldo + k0 + kg;
        *(uint4_ma*)o       = make_uint4(w[0], w[1], w[2], w[3]);
        *(uint4_ma*)(o + 8) = make_uint4(w[4], w[5], w[6], w[7]);
    }
}

// ============ prep 1b: Wc_s = Wrq[:, s*64:+64] @ Wrk^T -> Wt rows [1024+s*64, +64) ============
__global__ __launch_bounds__(256) void prep_wc_k(
    const float* __restrict__ Wrq, const float* __restrict__ Wrk,
    unsigned short* __restrict__ Wt)
{
    __shared__ float sQ[64][65];
    __shared__ float sK[64][65];
    const int tid = threadIdx.x;
    const int s = blockIdx.x;
    const int k0 = blockIdx.y * 64;

#pragma unroll
    for (int p = 0; p < 4; ++p) {
        int row = (tid >> 4) + p * 16;
        int col = (tid & 15) * 4;
        float4 w = *(const float4*)&Wrk[(size_t)row * 64 + col];
        sK[row][col + 0] = w.x; sK[row][col + 1] = w.y;
        sK[row][col + 2] = w.z; sK[row][col + 3] = w.w;
        float4 q = *(const float4*)&Wrq[(size_t)(k0 + row) * 512 + s * 64 + col];
        sQ[row][col + 0] = q.x; sQ[row][col + 1] = q.y;
        sQ[row][col + 2] = q.z; sQ[row][col + 3] = q.w;
    }
    __syncthreads();

    const int dd = tid >> 2;
    const int kq = (tid & 3) * 16;
    float acc[16];
#pragma unroll
    for (int j = 0; j < 16; ++j) acc[j] = 0.f;
    for (int e = 0; e < 64; ++e) {
        float w = sK[dd][e];
#pragma unroll
        for (int j = 0; j < 16; ++j) acc[j] += w * sQ[kq + j][e];
    }
    const float SC = 0.125f * 1.44269504089f;
    unsigned int w8[8];
#pragma unroll
    for (int j = 0; j < 8; ++j)
        w8[j] = (unsigned)f2bf(acc[2 * j] * SC) | ((unsigned)f2bf(acc[2 * j + 1] * SC) << 16);
    unsigned short* o = Wt + (size_t)(1024 + s * 64 + dd) * KDIM + k0 + kq;
    *(uint4_ma*)o       = make_uint4(w8[0], w8[1], w8[2], w8[3]);
    *(uint4_ma*)(o + 8) = make_uint4(w8[4], w8[5], w8[6], w8[7]);
}

// ============ prep 2: x -> bf16 hi/lo planes ============
__global__ __launch_bounds__(256) void prep_x_k(
    const float* __restrict__ x,
    unsigned short* __restrict__ xh, unsigned short* __restrict__ xl)
{
    const int total = 4096 * KDIM / 4;
    int idx = blockIdx.x * 256 + threadIdx.x;
    for (int i = idx; i < total; i += gridDim.x * 256) {
        float4 v = ((const float4_ma*)x)[i];
        ushort4 h, l;
        h.x = f2bf(v.x); l.x = f2bf(v.x - bf2f(h.x));
        h.y = f2bf(v.y); l.y = f2bf(v.y - bf2f(h.y));
        h.z = f2bf(v.z); l.z = f2bf(v.z - bf2f(h.z));
        h.w = f2bf(v.w); l.w = f2bf(v.w - bf2f(h.w));
        ((ushort4*)xh)[i] = h;
        ((ushort4*)xl)[i] = l;
    }
}

// ============ Kernel 1: projection GEMM (bf16 MFMA, split-x) ============
// Qb bf16 [bs][n][64]; Kf bf16 fragmented [bs][kt][frag(8)][lane(64)][8];
// RUb bf16 [bs][n][64] (x@Wc, scale folded); Vt bf16 [b][128][n]
__global__ __launch_bounds__(256) void proj_mfma_k(
    const unsigned short* __restrict__ xh, const unsigned short* __restrict__ xl,
    const unsigned short* __restrict__ Wt,
    unsigned short* __restrict__ Qb, unsigned short* __restrict__ Kf,
    unsigned short* __restrict__ RUb, unsigned short* __restrict__ Vt)
{
    __shared__ __align__(16) char smem[40960];
    const int tid = threadIdx.x;
    const int bn = blockIdx.x, bm = blockIdx.y;
    const int wid = tid >> 6, lane = tid & 63;
    const int wm = wid >> 1, wn = wid & 1;
    const int lrow = lane & 15, lgrp = lane >> 4;

    f32x4 acc[4][2];
#pragma unroll
    for (int i = 0; i < 4; ++i)
#pragma unroll
        for (int j = 0; j < 2; ++j) acc[i][j] = (f32x4){0.f, 0.f, 0.f, 0.f};

    for (int kt = 0; kt < KDIM / 64; ++kt) {
        __syncthreads();
#pragma unroll
        for (int p = 0; p < 4; ++p) {
            int c = tid + p * 256;
            int r = c >> 3, cc = c & 7;
            int off = (r * 128 + cc * 16) ^ ((r & 7) << 4);
            size_t g = (size_t)(bm * 128 + r) * KDIM + kt * 64 + cc * 8;
            *(uint4_ma*)(smem + off)         = *(const uint4_ma*)(xh + g);
            *(uint4_ma*)(smem + 16384 + off) = *(const uint4_ma*)(xl + g);
        }
#pragma unroll
        for (int p = 0; p < 2; ++p) {
            int c = tid + p * 256;
            int r = c >> 3, cc = c & 7;
            *(uint4_ma*)(smem + 32768 + ((r * 128 + cc * 16) ^ ((r & 7) << 4))) =
                *(const uint4_ma*)(Wt + (size_t)(bn * 64 + r) * KDIM + kt * 64 + cc * 8);
        }
        __syncthreads();
#pragma unroll
        for (int ks = 0; ks < 2; ++ks) {
            bf16x8 bfr[2];
#pragma unroll
            for (int nf = 0; nf < 2; ++nf) {
                int rb = wn * 32 + nf * 16 + lrow;
                bfr[nf] = *(bf16x8_ma*)(smem + 32768 + ((rb * 128 + ks * 64 + lgrp * 16) ^ ((rb & 7) << 4)));
            }
#pragma unroll
            for (int mf = 0; mf < 4; ++mf) {
                int ra = wm * 64 + mf * 16 + lrow;
                int offa = (ra * 128 + ks * 64 + lgrp * 16) ^ ((ra & 7) << 4);
                bf16x8 ah = *(bf16x8_ma*)(smem + offa);
                bf16x8 al = *(bf16x8_ma*)(smem + 16384 + offa);
#pragma unroll
                for (int nf = 0; nf < 2; ++nf) {
                    acc[mf][nf] = __builtin_amdgcn_mfma_f32_16x16x32_bf16(ah, bfr[nf], acc[mf][nf], 0, 0, 0);
                    acc[mf][nf] = __builtin_amdgcn_mfma_f32_16x16x32_bf16(al, bfr[nf], acc[mf][nf], 0, 0, 0);
                }
            }
        }
    }

    const int g = bn >> 3;   // 0:Q 1:K 2:U 3:V
#pragma unroll
    for (int mf = 0; mf < 4; ++mf) {
#pragma unroll
        for (int nf = 0; nf < 2; ++nf) {
            int j0 = bn * 64 + wn * 32 + nf * 16 + lrow;
            int m0 = bm * 128 + wm * 64 + mf * 16 + lgrp * 4;
            if (g == 3) {
                int dv = j0 - 1536;
                int bb = m0 >> 11, seq = m0 & (NSEQ - 1);
                ushort4 h;
                h.x = f2bf(acc[mf][nf][0]); h.y = f2bf(acc[mf][nf][1]);
                h.z = f2bf(acc[mf][nf][2]); h.w = f2bf(acc[mf][nf][3]);
                *(ushort4*)&Vt[((size_t)bb * 128 + dv) * NSEQ + seq] = h;
            } else if (g == 1) {
                int s = (j0 >> 6) & 7, d = j0 & 63;
#pragma unroll
                for (int r = 0; r < 4; ++r) {
                    int m = m0 + r;
                    int bb = m >> 11, seq = m & (NSEQ - 1);
                    size_t base = ((size_t)(bb * NS + s)) * (NSEQ * DH)
                        + (size_t)(seq >> 6) * 4096
                        + ((((seq >> 4) & 3) * 2 + (d >> 5)) * 64
                           + ((d & 31) >> 3) * 16 + (seq & 15)) * 8 + (d & 7);
                    Kf[base] = f2bf(acc[mf][nf][r]);
                }
            } else {
                int s = (j0 >> 6) & 7, d = j0 & 63;
                unsigned short* basep = (g == 0) ? Qb : RUb;
#pragma unroll
                for (int r = 0; r < 4; ++r) {
                    int m = m0 + r;
                    int bb = m >> 11, seq = m & (NSEQ - 1);
                    basep[(((size_t)(bb * NS + s)) * NSEQ + seq) * DH + d] = f2bf(acc[mf][nf][r]);
                }
            }
        }
    }
}

// ============ Kernel 2: KV-split flash attention (partials) ============
// Grid 1024 = (bs 16) x (chunk 2) x (qt 32). 4 waves, wave owns q = wid*16+lrow.
// K: reg-dbuf (kfa/kfb) coalesced from fragmented Kfr, prefetch distance 2.
// V: LDS dbuf. Barriers are lgkmcnt-only (global prefetches stay in flight).
// Outputs: PT bf16 [bsc][n][128] (unnormalized O), ML f32 [bsc][2][n] (m, l).
// LDS 40960: V 2x16K @0 | P 4x2K @32768.
__global__ __launch_bounds__(256, 3) void attn_mfma_k(
    const unsigned short* __restrict__ Qb, const unsigned short* __restrict__ Kfr,
    const unsigned short* __restrict__ Vt,
    unsigned short* __restrict__ PT, float* __restrict__ ML)
{
    __shared__ __align__(16) char smem[40960];
    const int tid = threadIdx.x;
    const int g = blockIdx.x;
    const int orig = ((g & 7) << 7) + (g >> 3);   // XCD-contiguous remap (1024 = 8*128)
    const int qt = orig & 31, c = (orig >> 5) & 1, bs = orig >> 6;
    const int wid = tid >> 6, lane = tid & 63;
    const int lrow = lane & 15, lgrp = lane >> 4;

    const unsigned short* Qg = Qb + ((size_t)bs * NSEQ + qt * 64) * DH;
    const unsigned short* Kg = Kfr + (size_t)bs * (NSEQ * DH) + (size_t)c * 16 * 4096 + lane * 8;
    const unsigned short* Vg = Vt + (size_t)(bs >> 3) * 128 * NSEQ;

    bf16x8 qf[2];
    {
        const unsigned short* qrow = Qg + (wid * 16 + lrow) * DH + lgrp * 8;
        qf[0] = *(const bf16x8_ma*)(qrow);
        qf[1] = *(const bf16x8_ma*)(qrow + 32);
    }

    const int r0 = tid >> 3, cc = tid & 7;
    const unsigned short* vp = Vg + (size_t)r0 * NSEQ + cc * 8 + c * 1024;
    const int offv = (r0 * 128 + cc * 16) ^ ((r0 & 7) << 4);
    char* sP = smem + 32768 + wid * 2048;
    const int pswz = (lrow & 7) << 4;

    uint4 vreg[4];
    bf16x8 kfa[8], kfb[8];

#define LOADV(T) do {                                                         \
        const unsigned short* vq_ = vp + (T) * 64;                            \
        vreg[0] = *(const uint4_ma*)(vq_);                                    \
        vreg[1] = *(const uint4_ma*)(vq_ + (size_t)32 * NSEQ);                \
        vreg[2] = *(const uint4_ma*)(vq_ + (size_t)64 * NSEQ);                \
        vreg[3] = *(const uint4_ma*)(vq_ + (size_t)96 * NSEQ);                \
    } while (0)
#define STOREV(PAR) do {                                                      \
        char* vb_ = smem + (PAR) * 16384;                                     \
        *(uint4_ma*)(vb_ + offv)         = vreg[0];                           \
        *(uint4_ma*)(vb_ + offv + 4096)  = vreg[1];                           \
        *(uint4_ma*)(vb_ + offv + 8192)  = vreg[2];                           \
        *(uint4_ma*)(vb_ + offv + 12288) = vreg[3];                           \
    } while (0)
#define LOADK(KF, T) do {                                                     \
        const unsigned short* kq_ = Kg + (size_t)(T) * 4096;                  \
        _Pragma("unroll")                                                     \
        for (int i_ = 0; i_ < 8; ++i_)                                        \
            KF[i_] = *(const bf16x8_ma*)(kq_ + i_ * 512);                     \
    } while (0)
#define QKC(KF) do {                                                          \
        __builtin_amdgcn_s_setprio(1);                                        \
        _Pragma("unroll")                                                     \
        for (int nf_ = 0; nf_ < 4; ++nf_) {                                   \
            st[nf_] = (f32x4){0.f, 0.f, 0.f, 0.f};                            \
            st[nf_] = __builtin_amdgcn_mfma_f32_16x16x32_bf16(KF[nf_*2],   qf[0], st[nf_], 0, 0, 0); \
            st[nf_] = __builtin_amdgcn_mfma_f32_16x16x32_bf16(KF[nf_*2+1], qf[1], st[nf_], 0, 0, 0); \
        }                                                                     \
        __builtin_amdgcn_s_setprio(0);                                        \
    } while (0)
#define PVC(PAR) do {                                                         \
        const char* vb_ = smem + (PAR) * 16384;                               \
        __builtin_amdgcn_s_setprio(1);                                        \
        _Pragma("unroll")                                                     \
        for (int kkv_ = 0; kkv_ < 2; ++kkv_) {                                \
            bf16x8 pf_ = *(bf16x8_ma*)(sP + ((lrow * 128 + kkv_ * 64 + lgrp * 16) ^ pswz)); \
            _Pragma("unroll")                                                 \
            for (int df_ = 0; df_ < 8; ++df_) {                               \
                int row_ = df_ * 16 + lrow;                                   \
                bf16x8 vf_ = *(bf16x8_ma*)(vb_ + ((row_ * 128 + kkv_ * 64 + lgrp * 16) ^ ((row_ & 7) << 4))); \
                oacc[df_] = __builtin_amdgcn_mfma_f32_16x16x32_bf16(vf_, pf_, oacc[df_], 0, 0, 0); \
            }                                                                 \
        }                                                                     \
        __builtin_amdgcn_s_setprio(0);                                        \
    } while (0)
#define SMC() do {                                                            \
        float mx_ = st[0][0];                                                 \
        _Pragma("unroll")                                                     \
        for (int nf_ = 0; nf_ < 4; ++nf_)                                     \
            _Pragma("unroll")                                                 \
            for (int r_ = 0; r_ < 4; ++r_) mx_ = fmaxf(mx_, st[nf_][r_]);     \
        mx_ = fmaxf(mx_, __shfl_xor(mx_, 16));                                \
        mx_ = fmaxf(mx_, __shfl_xor(mx_, 32));                                \
        if (__any(mx_ > m_ + 8.f)) {                                          \
            float mnew_ = fmaxf(m_, mx_);                                     \
            float alpha_ = __builtin_exp2f(m_ - mnew_);                       \
            _Pragma("unroll")                                                 \
            for (int df_ = 0; df_ < 8; ++df_) oacc[df_] = oacc[df_] * alpha_; \
            l_ *= alpha_;                                                     \
            m_ = mnew_;                                                       \
        }                                                                     \
        float rs_ = 0.f;                                                      \
        _Pragma("unroll")                                                     \
        for (int nf_ = 0; nf_ < 4; ++nf_)                                     \
            _Pragma("unroll")                                                 \
            for (int r_ = 0; r_ < 4; ++r_) {                                  \
                float p_ = __builtin_exp2f(st[nf_][r_] - m_);                 \
                st[nf_][r_] = p_;                                             \
                rs_ += p_;                                                    \
            }                                                                 \
        rs_ += __shfl_xor(rs_, 16);                                           \
        rs_ += __shfl_xor(rs_, 32);                                           \
        l_ += rs_;                                                            \
        _Pragma("unroll")                                                     \
        for (int nf_ = 0; nf_ < 4; ++nf_) {                                   \
            uint2 w_;                                                         \
            w_.x = cvt_pk_bf16(st[nf_][0], st[nf_][1]);                       \
            w_.y = cvt_pk_bf16(st[nf_][2], st[nf_][3]);                       \
            *(uint2_ma*)(sP + ((lrow * 128 + nf_ * 32 + lgrp * 8) ^ pswz)) = w_; \
        }                                                                     \
    } while (0)
#define ITER(T, KF, CUR) do {                                                 \
        if ((T) + 1 < NT) STOREV((CUR) ^ 1);                                  \
        if ((T) + 2 < NT) LOADV((T) + 2);                                     \
        QKC(KF);                                                              \
        if ((T) + 2 < NT) LOADK(KF, (T) + 2);                                 \
        SMC();                                                                \
        PVC(CUR);                                                             \
        if ((T) + 1 < NT) BAR();                                              \
    } while (0)

    f32x4 oacc[8];
#pragma unroll
    for (int df = 0; df < 8; ++df) oacc[df] = (f32x4){0.f, 0.f, 0.f, 0.f};
    float m_ = -1e30f, l_ = 0.f;
    f32x4 st[4];

    const int NT = 16;   // 1024 kv per chunk

    LOADV(0);
    LOADK(kfa, 0);
    LOADK(kfb, 1);
    STOREV(0);
    LOADV(1);
    BAR();

#pragma unroll
    for (int t = 0; t < NT; t += 2) {
        ITER(t, kfa, 0);
        ITER(t + 1, kfb, 1);
    }

#undef LOADV
#undef STOREV
#undef LOADK
#undef QKC
#undef PVC
#undef SMC
#undef ITER

    // ---- write partials ----
    {
        const int n = qt * 64 + wid * 16 + lrow;
        const int bsc = bs * 2 + c;
        if (lgrp == 0) {
            ML[((size_t)bsc * 2 + 0) * NSEQ + n] = m_;
            ML[((size_t)bsc * 2 + 1) * NSEQ + n] = l_;
        }
        unsigned short* pd = PT + ((size_t)bsc * NSEQ + n) * 128 + lgrp * 4;
#pragma unroll
        for (int df = 0; df < 8; ++df) {
            uint2 w;
            w.x = cvt_pk_bf16(oacc[df][0], oacc[df][1]);
            w.y = cvt_pk_bf16(oacc[df][2], oacc[df][3]);
            *(uint2_ma*)(pd + df * 16) = w;
        }
    }
}

// ============ Kernel 2b: chunk reduce + fused retrieval epilogue ============
// Grid (32 nblk, 8 s, 2 b) x 256 thr. Thread = (n = nb*64 + tid&63, dg = tid>>6).
__global__ __launch_bounds__(256) void reduce_k(
    const unsigned short* __restrict__ PT, const float* __restrict__ ML,
    const unsigned short* __restrict__ RUb, unsigned short* __restrict__ O1b)
{
    __shared__ float sRed[4][64];
    __shared__ float sA[2][64];
    __shared__ float sHi[64][64];
    const int tid = threadIdx.x;
    const int n_l = tid & 63, dg = tid >> 6;
    const int s = blockIdx.y, b = blockIdx.z;
    const int bs = b * NS + s;
    const int n = blockIdx.x * 64 + n_l;

    const float m0 = ML[((size_t)(bs * 2 + 0) * 2 + 0) * NSEQ + n];
    const float l0 = ML[((size_t)(bs * 2 + 0) * 2 + 1) * NSEQ + n];
    const float m1 = ML[((size_t)(bs * 2 + 1) * 2 + 0) * NSEQ + n];
    const float l1 = ML[((size_t)(bs * 2 + 1) * 2 + 1) * NSEQ + n];
    const float M = fmaxf(m0, m1);
    const float w0 = __builtin_exp2f(m0 - M), w1 = __builtin_exp2f(m1 - M);
    const float L = l0 * w0 + l1 * w1;

    const unsigned short* p0 = PT + ((size_t)(bs * 2 + 0) * NSEQ + n) * 128 + dg * 32;
    const unsigned short* p1 = PT + ((size_t)(bs * 2 + 1) * NSEQ + n) * 128 + dg * 32;
    const unsigned short* ug = RUb + ((size_t)bs * NSEQ + n) * DH + (dg & 1) * 32;

    float O[32];
    float part = 0.f;
#pragma unroll
    for (int j = 0; j < 4; ++j) {
        uint4 a = *(const uint4_ma*)(p0 + j * 8);
        uint4 bq = *(const uint4_ma*)(p1 + j * 8);
        uint4 uu = *(const uint4_ma*)(ug + j * 8);
        unsigned int av[4] = {a.x, a.y, a.z, a.w};
        unsigned int bv[4] = {bq.x, bq.y, bq.z, bq.w};
        unsigned int uv[4] = {uu.x, uu.y, uu.z, uu.w};
#pragma unroll
        for (int k = 0; k < 4; ++k) {
            float o0 = w0 * bf2f((unsigned short)(av[k] & 0xffff)) +
                       w1 * bf2f((unsigned short)(bv[k] & 0xffff));
            float o1 = w0 * bf2f((unsigned short)(av[k] >> 16)) +
                       w1 * bf2f((unsigned short)(bv[k] >> 16));
            O[j * 8 + k * 2]     = o0;
            O[j * 8 + k * 2 + 1] = o1;
            part += o0 * bf2f((unsigned short)(uv[k] & 0xffff));
            part += o1 * bf2f((unsigned short)(uv[k] >> 16));
        }
    }
    sRed[dg][n_l] = part;
    if (dg >= 2) {
#pragma unroll
        for (int i = 0; i < 32; ++i) sHi[(dg - 2) * 32 + i][n_l] = O[i];
    }
    __syncthreads();
    if (dg == 0) {
        float s0 = sRed[0][n_l] + sRed[1][n_l];
        float s1 = sRed[2][n_l] + sRed[3][n_l];
        float invL = 1.f / L;
        float r0 = s0 * invL, r1 = s1 * invL;
        float mm = fmaxf(r0, r1);
        float e0 = __builtin_exp2f(r0 - mm), e1 = __builtin_exp2f(r1 - mm);
        float wv = invL / (e0 + e1);
        sA[0][n_l] = e0 * wv;
        sA[1][n_l] = e1 * wv;
    }
    __syncthreads();
    if (dg < 2) {
        const float a0 = sA[0][n_l], a1 = sA[1][n_l];
        unsigned short* dst = O1b + ((size_t)(b * NSEQ + n)) * (NS * DH) + s * DH + dg * 32;
#pragma unroll
        for (int j = 0; j < 4; ++j) {
            float o[8];
#pragma unroll
            for (int k = 0; k < 8; ++k)
                o[k] = a0 * O[j * 8 + k] + a1 * sHi[dg * 32 + j * 8 + k][n_l];
            uint4 w;
            w.x = cvt_pk_bf16(o[0], o[1]);
            w.y = cvt_pk_bf16(o[2], o[3]);
            w.z = cvt_pk_bf16(o[4], o[5]);
            w.w = cvt_pk_bf16(o[6], o[7]);
            *(uint4_ma*)(dst + j * 8) = w;
        }
    }
}

// ============ Kernel 3: output GEMM (bf16 MFMA) ============
__global__ __launch_bounds__(256) void out_mfma_k(
    const unsigned short* __restrict__ A, const unsigned short* __restrict__ Bw,
    float* __restrict__ C)
{
    __shared__ __align__(16) char smem[24576];
    const int tid = threadIdx.x;
    const int bn = blockIdx.x, bm = blockIdx.y;
    const int wid = tid >> 6, lane = tid & 63;
    const int wm = wid >> 1, wn = wid & 1;
    const int lrow = lane & 15, lgrp = lane >> 4;
    const int KD = NS * DH;   // 512

    f32x4 acc[4][2];
#pragma unroll
    for (int i = 0; i < 4; ++i)
#pragma unroll
        for (int j = 0; j < 2; ++j) acc[i][j] = (f32x4){0.f, 0.f, 0.f, 0.f};

    for (int kt = 0; kt < KD / 64; ++kt) {
        __syncthreads();
#pragma unroll
        for (int p = 0; p < 4; ++p) {
            int c = tid + p * 256;
            int r = c >> 3, cc = c & 7;
            *(uint4_ma*)(smem + ((r * 128 + cc * 16) ^ ((r & 7) << 4))) =
                *(const uint4_ma*)(A + (size_t)(bm * 128 + r) * KD + kt * 64 + cc * 8);
        }
#pragma unroll
        for (int p = 0; p < 2; ++p) {
            int c = tid + p * 256;
            int r = c >> 3, cc = c & 7;
            *(uint4_ma*)(smem + 16384 + ((r * 128 + cc * 16) ^ ((r & 7) << 4))) =
                *(const uint4_ma*)(Bw + (size_t)(bn * 64 + r) * KD + kt * 64 + cc * 8);
        }
        __syncthreads();
#pragma unroll
        for (int ks = 0; ks < 2; ++ks) {
            bf16x8 bfr[2];
#pragma unroll
            for (int nf = 0; nf < 2; ++nf) {
                int rb = wn * 32 + nf * 16 + lrow;
                bfr[nf] = *(bf16x8_ma*)(smem + 16384 + ((rb * 128 + ks * 64 + lgrp * 16) ^ ((rb & 7) << 4)));
            }
#pragma unroll
            for (int mf = 0; mf < 4; ++mf) {
                int ra = wm * 64 + mf * 16 + lrow;
                bf16x8 af = *(bf16x8_ma*)(smem + ((ra * 128 + ks * 64 + lgrp * 16) ^ ((ra & 7) << 4)));
#pragma unroll
                for (int nf = 0; nf < 2; ++nf)
                    acc[mf][nf] = __builtin_amdgcn_mfma_f32_16x16x32_bf16(af, bfr[nf], acc[mf][nf], 0, 0, 0);
            }
        }
    }

#pragma unroll
    for (int mf = 0; mf < 4; ++mf) {
#pragma unroll
        for (int nf = 0; nf < 2; ++nf) {
            int j0 = bn * 64 + wn * 32 + nf * 16 + lrow;
            int m0 = bm * 128 + wm * 64 + mf * 16 + lgrp * 4;
#pragma unroll
            for (int r = 0; r < 4; ++r)
                C[(size_t)(m0 + r) * KDIM + j0] = acc[mf][nf][r];
        }
    }
}

extern "C" void kernel_launch(void* const* d_in, const int* in_sizes, int n_in,
                              void* d_out, int out_size, void* d_ws, size_t ws_size,
                              hipStream_t stream)
{
    const float* x    = (const float*)d_in[0];
    const float* Wsq  = (const float*)d_in[1];
    const float* Wsk  = (const float*)d_in[2];
    const float* Wrv  = (const float*)d_in[3];
    const float* Wrq  = (const float*)d_in[4];
    const float* Wrk  = (const float*)d_in[5];
    const float* Wout = (const float*)d_in[6];
    float* out = (float*)d_out;

    // workspace layout, 37.25 MB total (byte offsets):
    //  0MB  RUb  bf16 [16][2048][64]                (4 MB)
    //  4MB  Wot  bf16 [1024][512]                   (1 MB)
    //  5MB  Qb   bf16 [16][2048][64]                (4 MB)
    //  9MB  Kfr  bf16 fragmented                    (4 MB)
    // 13MB  Vtb  bf16 [2][128][2048]                (1 MB)
    // 14MB  xh (8MB) | 22MB xl (8MB) | 30MB Wt (3.25MB)   [live during proj]
    // 14MB  PT  bf16 [32][2048][128] (16MB, overlays xh+xl after proj)
    // 30MB  ML  f32  [32][2][2048]   (0.5MB, overlays Wt after proj)
    // 33.25MB O1b bf16 [2][2048][512] (4 MB)        -> ends 37.25MB
    char* base = (char*)d_ws;
    unsigned short* RUb = (unsigned short*)(base);
    unsigned short* Wot = (unsigned short*)(base + (size_t)4 * 1048576);
    unsigned short* Qb  = (unsigned short*)(base + (size_t)5 * 1048576);
    unsigned short* Kfr = (unsigned short*)(base + (size_t)9 * 1048576);
    unsigned short* Vtb = (unsigned short*)(base + (size_t)13 * 1048576);
    unsigned short* xh  = (unsigned short*)(base + (size_t)14 * 1048576);
    unsigned short* xl  = (unsigned short*)(base + (size_t)22 * 1048576);
    unsigned short* Wt  = (unsigned short*)(base + (size_t)30 * 1048576);
    unsigned short* PT  = xh;
    float*          ML  = (float*)(base + (size_t)30 * 1048576);
    unsigned short* O1b = (unsigned short*)(base + (size_t)34865152);

    prep_w_k<<<544, 256, 0, stream>>>(Wsq, Wsk, Wrq, Wrv, Wout, Wt, Wot);
    prep_wc_k<<<dim3(8, 16), 256, 0, stream>>>(Wrq, Wrk, Wt);
    prep_x_k<<<2048, 256, 0, stream>>>(x, xh, xl);
    proj_mfma_k<<<dim3(26, 32), 256, 0, stream>>>(xh, xl, Wt, Qb, Kfr, RUb, Vtb);
    attn_mfma_k<<<1024, 256, 0, stream>>>(Qb, Kfr, Vtb, PT, ML);
    reduce_k<<<dim3(32, 8, 2), 256, 0, stream>>>(PT, ML, RUb, O1b);
    out_mfma_k<<<dim3(16, 32), 256, 0, stream>>>(O1b, Wot, out);
}

// Round 9
// 182.095 us; speedup vs baseline: 1.1674x; 1.1674x over previous
//
#include <hip/hip_runtime.h>

#define NSEQ 2048
#define KDIM 1024
#define DH   64
#define NS   8
#define NR   2

typedef short bf16x8 __attribute__((ext_vector_type(8)));
typedef float f32x4  __attribute__((ext_vector_type(4)));

typedef unsigned short ushort_ma __attribute__((may_alias));
typedef bf16x8         bf16x8_ma __attribute__((may_alias));
typedef uint4          uint4_ma  __attribute__((may_alias));
typedef uint2          uint2_ma  __attribute__((may_alias));
typedef float4         float4_ma __attribute__((may_alias));

__device__ __forceinline__ unsigned short f2bf(float f) {
    unsigned int u = __builtin_bit_cast(unsigned int, f);
    u = (u + 0x7FFFu + ((u >> 16) & 1u)) >> 16;   // RTN-even
    return (unsigned short)u;
}
__device__ __forceinline__ float bf2f(unsigned short h) {
    unsigned int u = ((unsigned int)h) << 16;
    return __builtin_bit_cast(float, u);
}
__device__ __forceinline__ unsigned int cvt_pk_bf16(float lo, float hi) {
    unsigned int r;
    asm("v_cvt_pk_bf16_f32 %0, %1, %2" : "=v"(r) : "v"(lo), "v"(hi));
    return r;
}
// async global->LDS, 16B/lane. LDS dest = wave-uniform base + lane*16 (m104).
__device__ __forceinline__ void gld_lds16(void* lptr, const void* gptr) {
    __builtin_amdgcn_global_load_lds(
        (const __attribute__((address_space(1))) unsigned int*)gptr,
        (__attribute__((address_space(3))) unsigned int*)lptr, 16, 0, 0);
}

// ============ prep 1: weight transpose + f32->bf16 ============
// Wt[1664][1024] = [(0.125*log2e)*Wsq | Wsk | (Wrq sect by prep_wc) | Wrv]^T
// Wot[1024][512] = Wout^T
__global__ __launch_bounds__(256) void prep_w_k(
    const float* __restrict__ Wsq, const float* __restrict__ Wsk,
    const float* __restrict__ Wrq, const float* __restrict__ Wrv,
    const float* __restrict__ Wout,
    unsigned short* __restrict__ Wt, unsigned short* __restrict__ Wot)
{
    __shared__ float sT[64][65];
    const int tid = threadIdx.x;
    const int bid = blockIdx.x;

    const float* src; int ldw, k0, n0, scol, ldo;
    unsigned short* dst;
    float sc = 1.0f;
    if (bid < 416) {
        int kt = bid / 26, nt = bid % 26;
        k0 = kt * 64; n0 = nt * 64;
        if (n0 >= 1024 && n0 < 1536) return;
        if (n0 < 512)       { src = Wsq; ldw = 512; scol = n0;        sc = 0.125f * 1.44269504089f; }
        else if (n0 < 1024) { src = Wsk; ldw = 512; scol = n0 - 512;  }
        else                { src = Wrv; ldw = 128; scol = n0 - 1536; }
        dst = Wt; ldo = KDIM;
    } else {
        int r = bid - 416;
        int kt = r >> 4, nt = r & 15;
        k0 = kt * 64; n0 = nt * 64; scol = n0;
        src = Wout; ldw = KDIM;
        dst = Wot; ldo = 512;
    }

#pragma unroll
    for (int p = 0; p < 4; ++p) {
        int row = (tid >> 4) + p * 16;
        int col = (tid & 15) * 4;
        float4 v = *(const float4*)&src[(size_t)(k0 + row) * ldw + scol + col];
        sT[row][col + 0] = v.x; sT[row][col + 1] = v.y;
        sT[row][col + 2] = v.z; sT[row][col + 3] = v.w;
    }
    __syncthreads();

    {
        int n_l = tid >> 2, kg = (tid & 3) * 16;
        unsigned int w[8];
#pragma unroll
        for (int j = 0; j < 8; ++j) {
            unsigned short a = f2bf(sT[kg + 2 * j][n_l] * sc);
            unsigned short b = f2bf(sT[kg + 2 * j + 1][n_l] * sc);
            w[j] = (unsigned)a | ((unsigned)b << 16);
        }
        unsigned short* o = dst + (size_t)(n0 + n_l) * ldo + k0 + kg;
        *(uint4_ma*)o       = make_uint4(w[0], w[1], w[2], w[3]);
        *(uint4_ma*)(o + 8) = make_uint4(w[4], w[5], w[6], w[7]);
    }
}

// ============ prep 1b: Wc_s = Wrq[:, s*64:+64] @ Wrk^T -> Wt rows [1024+s*64, +64) ============
__global__ __launch_bounds__(256) void prep_wc_k(
    const float* __restrict__ Wrq, const float* __restrict__ Wrk,
    unsigned short* __restrict__ Wt)
{
    __shared__ float sQ[64][65];
    __shared__ float sK[64][65];
    const int tid = threadIdx.x;
    const int s = blockIdx.x;
    const int k0 = blockIdx.y * 64;

#pragma unroll
    for (int p = 0; p < 4; ++p) {
        int row = (tid >> 4) + p * 16;
        int col = (tid & 15) * 4;
        float4 w = *(const float4*)&Wrk[(size_t)row * 64 + col];
        sK[row][col + 0] = w.x; sK[row][col + 1] = w.y;
        sK[row][col + 2] = w.z; sK[row][col + 3] = w.w;
        float4 q = *(const float4*)&Wrq[(size_t)(k0 + row) * 512 + s * 64 + col];
        sQ[row][col + 0] = q.x; sQ[row][col + 1] = q.y;
        sQ[row][col + 2] = q.z; sQ[row][col + 3] = q.w;
    }
    __syncthreads();

    const int dd = tid >> 2;
    const int kq = (tid & 3) * 16;
    float acc[16];
#pragma unroll
    for (int j = 0; j < 16; ++j) acc[j] = 0.f;
    for (int e = 0; e < 64; ++e) {
        float w = sK[dd][e];
#pragma unroll
        for (int j = 0; j < 16; ++j) acc[j] += w * sQ[kq + j][e];
    }
    const float SC = 0.125f * 1.44269504089f;
    unsigned int w8[8];
#pragma unroll
    for (int j = 0; j < 8; ++j)
        w8[j] = (unsigned)f2bf(acc[2 * j] * SC) | ((unsigned)f2bf(acc[2 * j + 1] * SC) << 16);
    unsigned short* o = Wt + (size_t)(1024 + s * 64 + dd) * KDIM + k0 + kq;
    *(uint4_ma*)o       = make_uint4(w8[0], w8[1], w8[2], w8[3]);
    *(uint4_ma*)(o + 8) = make_uint4(w8[4], w8[5], w8[6], w8[7]);
}

// ============ prep 2: x -> bf16 hi/lo planes ============
__global__ __launch_bounds__(256) void prep_x_k(
    const float* __restrict__ x,
    unsigned short* __restrict__ xh, unsigned short* __restrict__ xl)
{
    const int total = 4096 * KDIM / 4;
    int idx = blockIdx.x * 256 + threadIdx.x;
    for (int i = idx; i < total; i += gridDim.x * 256) {
        float4 v = ((const float4_ma*)x)[i];
        ushort4 h, l;
        h.x = f2bf(v.x); l.x = f2bf(v.x - bf2f(h.x));
        h.y = f2bf(v.y); l.y = f2bf(v.y - bf2f(h.y));
        h.z = f2bf(v.z); l.z = f2bf(v.z - bf2f(h.z));
        h.w = f2bf(v.w); l.w = f2bf(v.w - bf2f(h.w));
        ((ushort4*)xh)[i] = h;
        ((ushort4*)xl)[i] = l;
    }
}

// ============ Kernel 1: projection GEMM (bf16 MFMA, split-x) ============
// Staging via global_load_lds width=16: LINEAR LDS dest + inverse-swizzled global
// source + swizzled reads (rule #21 / m201 pattern). Reads unchanged.
__global__ __launch_bounds__(256) void proj_mfma_k(
    const unsigned short* __restrict__ xh, const unsigned short* __restrict__ xl,
    const unsigned short* __restrict__ Wt,
    unsigned short* __restrict__ Qb, unsigned short* __restrict__ Kb,
    float* __restrict__ RU, unsigned short* __restrict__ Vt)
{
    __shared__ __align__(16) char smem[40960];
    const int tid = threadIdx.x;
    const int bn = blockIdx.x, bm = blockIdx.y;
    const int wid = tid >> 6, lane = tid & 63;
    const int wm = wid >> 1, wn = wid & 1;
    const int lrow = lane & 15, lgrp = lane >> 4;
    const int lr = lane >> 3, lc = lane & 7;   // staging coords

    f32x4 acc[4][2];
#pragma unroll
    for (int i = 0; i < 4; ++i)
#pragma unroll
        for (int j = 0; j < 2; ++j) acc[i][j] = (f32x4){0.f, 0.f, 0.f, 0.f};

    for (int kt = 0; kt < KDIM / 64; ++kt) {
        __syncthreads();
        // xh/xl tiles: 16 segments x 1KB each; 4 per wave
#pragma unroll
        for (int i = 0; i < 4; ++i) {
            int seg = wid * 4 + i;
            int r = seg * 8 + lr;
            size_t goff = (size_t)(bm * 128 + r) * KDIM + kt * 64 + (lc ^ (r & 7)) * 8;
            gld_lds16(smem + seg * 1024, xh + goff);
            gld_lds16(smem + 16384 + seg * 1024, xl + goff);
        }
        // Wt tile: 8 segments; 2 per wave
#pragma unroll
        for (int i = 0; i < 2; ++i) {
            int seg = wid * 2 + i;
            int r = seg * 8 + lr;
            gld_lds16(smem + 32768 + seg * 1024,
                      Wt + (size_t)(bn * 64 + r) * KDIM + kt * 64 + (lc ^ (r & 7)) * 8);
        }
        __syncthreads();
#pragma unroll
        for (int ks = 0; ks < 2; ++ks) {
            bf16x8 bfr[2];
#pragma unroll
            for (int nf = 0; nf < 2; ++nf) {
                int rb = wn * 32 + nf * 16 + lrow;
                bfr[nf] = *(bf16x8_ma*)(smem + 32768 + ((rb * 128 + ks * 64 + lgrp * 16) ^ ((rb & 7) << 4)));
            }
#pragma unroll
            for (int mf = 0; mf < 4; ++mf) {
                int ra = wm * 64 + mf * 16 + lrow;
                int offa = (ra * 128 + ks * 64 + lgrp * 16) ^ ((ra & 7) << 4);
                bf16x8 ah = *(bf16x8_ma*)(smem + offa);
                bf16x8 al = *(bf16x8_ma*)(smem + 16384 + offa);
#pragma unroll
                for (int nf = 0; nf < 2; ++nf) {
                    acc[mf][nf] = __builtin_amdgcn_mfma_f32_16x16x32_bf16(ah, bfr[nf], acc[mf][nf], 0, 0, 0);
                    acc[mf][nf] = __builtin_amdgcn_mfma_f32_16x16x32_bf16(al, bfr[nf], acc[mf][nf], 0, 0, 0);
                }
            }
        }
    }

    const int g = bn >> 3;   // 0:Q 1:K 2:U 3:V
#pragma unroll
    for (int mf = 0; mf < 4; ++mf) {
#pragma unroll
        for (int nf = 0; nf < 2; ++nf) {
            int j0 = bn * 64 + wn * 32 + nf * 16 + lrow;
            int m0 = bm * 128 + wm * 64 + mf * 16 + lgrp * 4;
            if (g == 3) {
                int dv = j0 - 1536;
                int bb = m0 >> 11, seq = m0 & (NSEQ - 1);
                ushort4 h;
                h.x = f2bf(acc[mf][nf][0]); h.y = f2bf(acc[mf][nf][1]);
                h.z = f2bf(acc[mf][nf][2]); h.w = f2bf(acc[mf][nf][3]);
                *(ushort4*)&Vt[((size_t)bb * 128 + dv) * NSEQ + seq] = h;
            } else {
                int s = (j0 >> 6) & 7, d = j0 & 63;
#pragma unroll
                for (int r = 0; r < 4; ++r) {
                    int m = m0 + r;
                    int bb = m >> 11, seq = m & (NSEQ - 1);
                    size_t idx = (((size_t)(bb * NS + s)) * NSEQ + seq) * DH + d;
                    if (g == 2)      RU[idx] = acc[mf][nf][r];
                    else if (g == 0) Qb[idx] = f2bf(acc[mf][nf][r]);
                    else             Kb[idx] = f2bf(acc[mf][nf][r]);
                }
            }
        }
    }
}

// ============ Kernel 2: MFMA flash attention, dbuf K/V, fused retrieval via U ============
// (R5 verbatim — empirically best attention: 110 us)
__global__ __launch_bounds__(256) void attn_mfma_k(
    const unsigned short* __restrict__ Qb, const unsigned short* __restrict__ Kb,
    const unsigned short* __restrict__ Vt, const float* __restrict__ RU,
    unsigned short* __restrict__ O1b)
{
    __shared__ __align__(16) char smem[57344];
    const int tid = threadIdx.x;
    const int qt = blockIdx.x, s = blockIdx.y, b = blockIdx.z;
    const int wid = tid >> 6, lane = tid & 63;
    const int lrow = lane & 15, lgrp = lane >> 4;

    const unsigned short* Qg = Qb + (((size_t)(b * NS + s)) * NSEQ + qt * 64) * DH;
    const unsigned short* Kg = Kb + (((size_t)(b * NS + s)) * NSEQ) * DH;
    const unsigned short* Vg = Vt + (size_t)b * 128 * NSEQ;

    bf16x8 qf[2];
    {
        const unsigned short* qrow = Qg + (wid * 16 + lrow) * DH + lgrp * 8;
        qf[0] = *(const bf16x8_ma*)(qrow);
        qf[1] = *(const bf16x8_ma*)(qrow + 32);
    }

    const int r0 = tid >> 3, cc = tid & 7;
    const unsigned short* kp = Kg + (size_t)r0 * DH + cc * 8;
    const unsigned short* vp = Vg + (size_t)r0 * NSEQ + cc * 8;
    const int offk = (r0 * 128 + cc * 16) ^ ((r0 & 7) << 4);
    char* sPw = smem + 49152 + wid * 2048;

    uint4 kreg[2], vreg[4];
#define LOADT(KT) do {                                                        \
        const unsigned short* kq_ = kp + (size_t)(KT) * 64 * DH;              \
        kreg[0] = *(const uint4_ma*)(kq_);                                    \
        kreg[1] = *(const uint4_ma*)(kq_ + 32 * DH);                          \
        const unsigned short* vq_ = vp + (KT) * 64;                           \
        vreg[0] = *(const uint4_ma*)(vq_);                                    \
        vreg[1] = *(const uint4_ma*)(vq_ + (size_t)32 * NSEQ);                \
        vreg[2] = *(const uint4_ma*)(vq_ + (size_t)64 * NSEQ);                \
        vreg[3] = *(const uint4_ma*)(vq_ + (size_t)96 * NSEQ);                \
    } while (0)
#define STORET(BUF) do {                                                      \
        char* kb_ = smem + (BUF) * 8192;                                      \
        *(uint4_ma*)(kb_ + offk)        = kreg[0];                            \
        *(uint4_ma*)(kb_ + offk + 4096) = kreg[1];                            \
        char* vb_ = smem + 16384 + (BUF) * 16384;                             \
        *(uint4_ma*)(vb_ + offk)         = vreg[0];                           \
        *(uint4_ma*)(vb_ + offk + 4096)  = vreg[1];                           \
        *(uint4_ma*)(vb_ + offk + 8192)  = vreg[2];                           \
        *(uint4_ma*)(vb_ + offk + 12288) = vreg[3];                           \
    } while (0)

    f32x4 oacc[8];
#pragma unroll
    for (int df = 0; df < 8; ++df) oacc[df] = (f32x4){0.f, 0.f, 0.f, 0.f};
    float m_ = -1e30f, l_ = 0.f;

    const int NT = NSEQ / 64;
    LOADT(0);
    STORET(0);
    LOADT(1);

    for (int kt = 0; kt < NT; ++kt) {
        const int cur = kt & 1;
        __syncthreads();
        if (kt + 1 < NT) STORET(cur ^ 1);
        if (kt + 2 < NT) LOADT(kt + 2);

        const char* kb = smem + cur * 8192;
        const char* vb = smem + 16384 + cur * 16384;

        f32x4 st[4];
#pragma unroll
        for (int nf = 0; nf < 4; ++nf) st[nf] = (f32x4){0.f, 0.f, 0.f, 0.f};
        __builtin_amdgcn_s_setprio(1);
#pragma unroll
        for (int kk = 0; kk < 2; ++kk) {
#pragma unroll
            for (int nf = 0; nf < 4; ++nf) {
                int row = nf * 16 + lrow;
                bf16x8 kf = *(bf16x8_ma*)(kb + ((row * 128 + kk * 64 + lgrp * 16) ^ ((row & 7) << 4)));
                st[nf] = __builtin_amdgcn_mfma_f32_16x16x32_bf16(kf, qf[kk], st[nf], 0, 0, 0);
            }
        }
        __builtin_amdgcn_s_setprio(0);

        float mx = st[0][0];
#pragma unroll
        for (int nf = 0; nf < 4; ++nf)
#pragma unroll
            for (int r = 0; r < 4; ++r) mx = fmaxf(mx, st[nf][r]);
        mx = fmaxf(mx, __shfl_xor(mx, 16));
        mx = fmaxf(mx, __shfl_xor(mx, 32));
        if (__any(mx > m_ + 8.f)) {
            float mnew = fmaxf(m_, mx);
            float alpha = __builtin_exp2f(m_ - mnew);
#pragma unroll
            for (int df = 0; df < 8; ++df) oacc[df] = oacc[df] * alpha;
            l_ *= alpha;
            m_ = mnew;
        }
        float rs = 0.f;
#pragma unroll
        for (int nf = 0; nf < 4; ++nf)
#pragma unroll
            for (int r = 0; r < 4; ++r) {
                float p = __builtin_exp2f(st[nf][r] - m_);
                st[nf][r] = p;
                rs += p;
            }
        rs += __shfl_xor(rs, 16);
        rs += __shfl_xor(rs, 32);
        l_ += rs;

        const int pswz = (lrow & 7) << 4;
#pragma unroll
        for (int nf = 0; nf < 4; ++nf) {
            uint2 w;
            w.x = cvt_pk_bf16(st[nf][0], st[nf][1]);
            w.y = cvt_pk_bf16(st[nf][2], st[nf][3]);
            *(uint2_ma*)(sPw + ((lrow * 128 + nf * 32 + lgrp * 8) ^ pswz)) = w;
        }

        __builtin_amdgcn_s_setprio(1);
#pragma unroll
        for (int kkv = 0; kkv < 2; ++kkv) {
            bf16x8 pf = *(bf16x8_ma*)(sPw + ((lrow * 128 + kkv * 64 + lgrp * 16) ^ pswz));
#pragma unroll
            for (int df = 0; df < 8; ++df) {
                int row = df * 16 + lrow;
                bf16x8 vf = *(bf16x8_ma*)(vb + ((row * 128 + kkv * 64 + lgrp * 16) ^ ((row & 7) << 4)));
                oacc[df] = __builtin_amdgcn_mfma_f32_16x16x32_bf16(vf, pf, oacc[df], 0, 0, 0);
            }
        }
        __builtin_amdgcn_s_setprio(0);
    }
#undef LOADT
#undef STORET

    // retrieval epilogue (register-only; u = x@Wc already has 0.125*log2e)
    {
        const int n = qt * 64 + wid * 16 + lrow;
        const float* ug = RU + ((((size_t)(b * NS + s)) * NSEQ) + n) * DH + lgrp * 4;
        float s0 = 0.f, s1 = 0.f;
#pragma unroll
        for (int df = 0; df < 4; ++df) {
            float4 u4 = *(const float4_ma*)(ug + df * 16);
            s0 += oacc[df][0] * u4.x + oacc[df][1] * u4.y + oacc[df][2] * u4.z + oacc[df][3] * u4.w;
            s1 += oacc[df + 4][0] * u4.x + oacc[df + 4][1] * u4.y + oacc[df + 4][2] * u4.z + oacc[df + 4][3] * u4.w;
        }
        s0 += __shfl_xor(s0, 16); s0 += __shfl_xor(s0, 32);
        s1 += __shfl_xor(s1, 16); s1 += __shfl_xor(s1, 32);
        float invl = 1.f / l_;
        float r0v = s0 * invl, r1v = s1 * invl;
        float mm = fmaxf(r0v, r1v);
        float e0 = __builtin_exp2f(r0v - mm), e1 = __builtin_exp2f(r1v - mm);
        float w = invl / (e0 + e1);
        float a0 = e0 * w, a1 = e1 * w;

        unsigned short* dst = O1b + ((size_t)(b * NSEQ + n)) * (NS * DH) + s * DH + lgrp * 4;
#pragma unroll
        for (int df = 0; df < 4; ++df) {
            float c0 = a0 * oacc[df][0] + a1 * oacc[df + 4][0];
            float c1 = a0 * oacc[df][1] + a1 * oacc[df + 4][1];
            float c2 = a0 * oacc[df][2] + a1 * oacc[df + 4][2];
            float c3 = a0 * oacc[df][3] + a1 * oacc[df + 4][3];
            uint2 o2;
            o2.x = cvt_pk_bf16(c0, c1);
            o2.y = cvt_pk_bf16(c2, c3);
            *(uint2_ma*)(dst + df * 16) = o2;
        }
    }
}

// ============ Kernel 3: output GEMM (bf16 MFMA, global_load_lds staging) ============
__global__ __launch_bounds__(256) void out_mfma_k(
    const unsigned short* __restrict__ A, const unsigned short* __restrict__ Bw,
    float* __restrict__ C)
{
    __shared__ __align__(16) char smem[24576];
    const int tid = threadIdx.x;
    const int bn = blockIdx.x, bm = blockIdx.y;
    const int wid = tid >> 6, lane = tid & 63;
    const int wm = wid >> 1, wn = wid & 1;
    const int lrow = lane & 15, lgrp = lane >> 4;
    const int lr = lane >> 3, lc = lane & 7;
    const int KD = NS * DH;   // 512

    f32x4 acc[4][2];
#pragma unroll
    for (int i = 0; i < 4; ++i)
#pragma unroll
        for (int j = 0; j < 2; ++j) acc[i][j] = (f32x4){0.f, 0.f, 0.f, 0.f};

    for (int kt = 0; kt < KD / 64; ++kt) {
        __syncthreads();
#pragma unroll
        for (int i = 0; i < 4; ++i) {
            int seg = wid * 4 + i;
            int r = seg * 8 + lr;
            gld_lds16(smem + seg * 1024,
                      A + (size_t)(bm * 128 + r) * KD + kt * 64 + (lc ^ (r & 7)) * 8);
        }
#pragma unroll
        for (int i = 0; i < 2; ++i) {
            int seg = wid * 2 + i;
            int r = seg * 8 + lr;
            gld_lds16(smem + 16384 + seg * 1024,
                      Bw + (size_t)(bn * 64 + r) * KD + kt * 64 + (lc ^ (r & 7)) * 8);
        }
        __syncthreads();
#pragma unroll
        for (int ks = 0; ks < 2; ++ks) {
            bf16x8 bfr[2];
#pragma unroll
            for (int nf = 0; nf < 2; ++nf) {
                int rb = wn * 32 + nf * 16 + lrow;
                bfr[nf] = *(bf16x8_ma*)(smem + 16384 + ((rb * 128 + ks * 64 + lgrp * 16) ^ ((rb & 7) << 4)));
            }
#pragma unroll
            for (int mf = 0; mf < 4; ++mf) {
                int ra = wm * 64 + mf * 16 + lrow;
                bf16x8 af = *(bf16x8_ma*)(smem + ((ra * 128 + ks * 64 + lgrp * 16) ^ ((ra & 7) << 4)));
#pragma unroll
                for (int nf = 0; nf < 2; ++nf)
                    acc[mf][nf] = __builtin_amdgcn_mfma_f32_16x16x32_bf16(af, bfr[nf], acc[mf][nf], 0, 0, 0);
            }
        }
    }

#pragma unroll
    for (int mf = 0; mf < 4; ++mf) {
#pragma unroll
        for (int nf = 0; nf < 2; ++nf) {
            int j0 = bn * 64 + wn * 32 + nf * 16 + lrow;
            int m0 = bm * 128 + wm * 64 + mf * 16 + lgrp * 4;
#pragma unroll
            for (int r = 0; r < 4; ++r)
                C[(size_t)(m0 + r) * KDIM + j0] = acc[mf][nf][r];
        }
    }
}

extern "C" void kernel_launch(void* const* d_in, const int* in_sizes, int n_in,
                              void* d_out, int out_size, void* d_ws, size_t ws_size,
                              hipStream_t stream)
{
    const float* x    = (const float*)d_in[0];
    const float* Wsq  = (const float*)d_in[1];
    const float* Wsk  = (const float*)d_in[2];
    const float* Wrv  = (const float*)d_in[3];
    const float* Wrq  = (const float*)d_in[4];
    const float* Wrk  = (const float*)d_in[5];
    const float* Wout = (const float*)d_in[6];
    float* out = (float*)d_out;

    // workspace layout (37.3 MB) — R5 layout
    float* RU            = (float*)d_ws;                        // [2][8][2048][64] f32, 8 MB
    unsigned short* Wt   = (unsigned short*)(RU + (size_t)2 * NS * NSEQ * DH);  // [1664][1024], 3.25 MB
    unsigned short* Wot  = Wt + (size_t)1664 * KDIM;            // [1024][512], 1 MB
    unsigned short* Qb   = Wot + (size_t)KDIM * 512;            // [2][8][2048][64], 4 MB
    unsigned short* Kb   = Qb + (size_t)2 * NS * NSEQ * DH;     // 4 MB
    unsigned short* Vtb  = Kb + (size_t)2 * NS * NSEQ * DH;     // [2][128][2048], 1 MB
    unsigned short* xh   = Vtb + (size_t)2 * 128 * NSEQ;        // [4096][1024], 8 MB
    unsigned short* xl   = xh + (size_t)4096 * KDIM;            // 8 MB
    unsigned short* O1b  = xh;  // alias: xh dead after proj_mfma_k

    prep_w_k<<<544, 256, 0, stream>>>(Wsq, Wsk, Wrq, Wrv, Wout, Wt, Wot);
    prep_wc_k<<<dim3(8, 16), 256, 0, stream>>>(Wrq, Wrk, Wt);
    prep_x_k<<<2048, 256, 0, stream>>>(x, xh, xl);
    proj_mfma_k<<<dim3(26, 32), 256, 0, stream>>>(xh, xl, Wt, Qb, Kb, RU, Vtb);
    attn_mfma_k<<<dim3(NSEQ / 64, NS, 2), 256, 0, stream>>>(Qb, Kb, Vtb, RU, O1b);
    out_mfma_k<<<dim3(16, 32), 256, 0, stream>>>(O1b, Wot, out);
}

// Round 10
// 134.006 us; speedup vs baseline: 1.5863x; 1.3589x over previous
//
#include <hip/hip_runtime.h>

#define NSEQ 2048
#define KDIM 1024
#define DH   64
#define NS   8
#define NR   2

typedef short bf16x8 __attribute__((ext_vector_type(8)));
typedef float f32x4  __attribute__((ext_vector_type(4)));

typedef unsigned short ushort_ma __attribute__((may_alias));
typedef bf16x8         bf16x8_ma __attribute__((may_alias));
typedef uint4          uint4_ma  __attribute__((may_alias));
typedef uint2          uint2_ma  __attribute__((may_alias));
typedef float4         float4_ma __attribute__((may_alias));

__device__ __forceinline__ unsigned short f2bf(float f) {
    unsigned int u = __builtin_bit_cast(unsigned int, f);
    u = (u + 0x7FFFu + ((u >> 16) & 1u)) >> 16;   // RTN-even
    return (unsigned short)u;
}
__device__ __forceinline__ float bf2f(unsigned short h) {
    unsigned int u = ((unsigned int)h) << 16;
    return __builtin_bit_cast(float, u);
}
__device__ __forceinline__ unsigned int cvt_pk_bf16(float lo, float hi) {
    unsigned int r;
    asm("v_cvt_pk_bf16_f32 %0, %1, %2" : "=v"(r) : "v"(lo), "v"(hi));
    return r;
}
// async global->LDS, 16B/lane. LDS dest = wave-uniform base + lane*16 (m104).
__device__ __forceinline__ void gld_lds16(void* lptr, const void* gptr) {
    __builtin_amdgcn_global_load_lds(
        (const __attribute__((address_space(1))) unsigned int*)gptr,
        (__attribute__((address_space(3))) unsigned int*)lptr, 16, 0, 0);
}

// ============ prep 1: weight transpose + f32->bf16 ============
// Wt[1664][1024] = [(0.125*log2e)*Wsq | Wsk | (Wrq sect by prep_wc) | Wrv]^T
// Wot[1024][512] = Wout^T
__global__ __launch_bounds__(256) void prep_w_k(
    const float* __restrict__ Wsq, const float* __restrict__ Wsk,
    const float* __restrict__ Wrq, const float* __restrict__ Wrv,
    const float* __restrict__ Wout,
    unsigned short* __restrict__ Wt, unsigned short* __restrict__ Wot)
{
    __shared__ float sT[64][65];
    const int tid = threadIdx.x;
    const int bid = blockIdx.x;

    const float* src; int ldw, k0, n0, scol, ldo;
    unsigned short* dst;
    float sc = 1.0f;
    if (bid < 416) {
        int kt = bid / 26, nt = bid % 26;
        k0 = kt * 64; n0 = nt * 64;
        if (n0 >= 1024 && n0 < 1536) return;
        if (n0 < 512)       { src = Wsq; ldw = 512; scol = n0;        sc = 0.125f * 1.44269504089f; }
        else if (n0 < 1024) { src = Wsk; ldw = 512; scol = n0 - 512;  }
        else                { src = Wrv; ldw = 128; scol = n0 - 1536; }
        dst = Wt; ldo = KDIM;
    } else {
        int r = bid - 416;
        int kt = r >> 4, nt = r & 15;
        k0 = kt * 64; n0 = nt * 64; scol = n0;
        src = Wout; ldw = KDIM;
        dst = Wot; ldo = 512;
    }

#pragma unroll
    for (int p = 0; p < 4; ++p) {
        int row = (tid >> 4) + p * 16;
        int col = (tid & 15) * 4;
        float4 v = *(const float4*)&src[(size_t)(k0 + row) * ldw + scol + col];
        sT[row][col + 0] = v.x; sT[row][col + 1] = v.y;
        sT[row][col + 2] = v.z; sT[row][col + 3] = v.w;
    }
    __syncthreads();

    {
        int n_l = tid >> 2, kg = (tid & 3) * 16;
        unsigned int w[8];
#pragma unroll
        for (int j = 0; j < 8; ++j) {
            unsigned short a = f2bf(sT[kg + 2 * j][n_l] * sc);
            unsigned short b = f2bf(sT[kg + 2 * j + 1][n_l] * sc);
            w[j] = (unsigned)a | ((unsigned)b << 16);
        }
        unsigned short* o = dst + (size_t)(n0 + n_l) * ldo + k0 + kg;
        *(uint4_ma*)o       = make_uint4(w[0], w[1], w[2], w[3]);
        *(uint4_ma*)(o + 8) = make_uint4(w[4], w[5], w[6], w[7]);
    }
}

// ============ prep 1b: Wc_s = Wrq[:, s*64:+64] @ Wrk^T -> Wt rows [1024+s*64, +64) ============
__global__ __launch_bounds__(256) void prep_wc_k(
    const float* __restrict__ Wrq, const float* __restrict__ Wrk,
    unsigned short* __restrict__ Wt)
{
    __shared__ float sQ[64][65];
    __shared__ float sK[64][65];
    const int tid = threadIdx.x;
    const int s = blockIdx.x;
    const int k0 = blockIdx.y * 64;

#pragma unroll
    for (int p = 0; p < 4; ++p) {
        int row = (tid >> 4) + p * 16;
        int col = (tid & 15) * 4;
        float4 w = *(const float4*)&Wrk[(size_t)row * 64 + col];
        sK[row][col + 0] = w.x; sK[row][col + 1] = w.y;
        sK[row][col + 2] = w.z; sK[row][col + 3] = w.w;
        float4 q = *(const float4*)&Wrq[(size_t)(k0 + row) * 512 + s * 64 + col];
        sQ[row][col + 0] = q.x; sQ[row][col + 1] = q.y;
        sQ[row][col + 2] = q.z; sQ[row][col + 3] = q.w;
    }
    __syncthreads();

    const int dd = tid >> 2;
    const int kq = (tid & 3) * 16;
    float acc[16];
#pragma unroll
    for (int j = 0; j < 16; ++j) acc[j] = 0.f;
    for (int e = 0; e < 64; ++e) {
        float w = sK[dd][e];
#pragma unroll
        for (int j = 0; j < 16; ++j) acc[j] += w * sQ[kq + j][e];
    }
    const float SC = 0.125f * 1.44269504089f;
    unsigned int w8[8];
#pragma unroll
    for (int j = 0; j < 8; ++j)
        w8[j] = (unsigned)f2bf(acc[2 * j] * SC) | ((unsigned)f2bf(acc[2 * j + 1] * SC) << 16);
    unsigned short* o = Wt + (size_t)(1024 + s * 64 + dd) * KDIM + k0 + kq;
    *(uint4_ma*)o       = make_uint4(w8[0], w8[1], w8[2], w8[3]);
    *(uint4_ma*)(o + 8) = make_uint4(w8[4], w8[5], w8[6], w8[7]);
}

// ============ prep 2: x -> bf16 hi/lo planes ============
__global__ __launch_bounds__(256) void prep_x_k(
    const float* __restrict__ x,
    unsigned short* __restrict__ xh, unsigned short* __restrict__ xl)
{
    const int total = 4096 * KDIM / 4;
    int idx = blockIdx.x * 256 + threadIdx.x;
    for (int i = idx; i < total; i += gridDim.x * 256) {
        float4 v = ((const float4_ma*)x)[i];
        ushort4 h, l;
        h.x = f2bf(v.x); l.x = f2bf(v.x - bf2f(h.x));
        h.y = f2bf(v.y); l.y = f2bf(v.y - bf2f(h.y));
        h.z = f2bf(v.z); l.z = f2bf(v.z - bf2f(h.z));
        h.w = f2bf(v.w); l.w = f2bf(v.w - bf2f(h.w));
        ((ushort4*)xh)[i] = h;
        ((ushort4*)xl)[i] = l;
    }
}

// ============ Kernel 1: projection GEMM (bf16 MFMA, split-x) ============
// Outputs: Qb bf16 [bs][n][64];
//          Kf bf16 fragmented [bs][kt(32)][frag(8)=nf*2+kk][lane(64)][8];
//          Vf bf16 fragmented [b][kt(32)][frag(16)=df*2+kkv][lane(64)][8]
//            lane(lgrp,lrow): V[kv=kt*64+kkv*32+lgrp*8+j][d=df*16+lrow];
//          RU f32 [bs][n][64] (x@Wc, scale folded).
// Staging via global_load_lds (linear LDS dest + inverse-swizzled source).
__global__ __launch_bounds__(256) void proj_mfma_k(
    const unsigned short* __restrict__ xh, const unsigned short* __restrict__ xl,
    const unsigned short* __restrict__ Wt,
    unsigned short* __restrict__ Qb, unsigned short* __restrict__ Kf,
    float* __restrict__ RU, unsigned short* __restrict__ Vf)
{
    __shared__ __align__(16) char smem[40960];
    const int tid = threadIdx.x;
    const int bn = blockIdx.x, bm = blockIdx.y;
    const int wid = tid >> 6, lane = tid & 63;
    const int wm = wid >> 1, wn = wid & 1;
    const int lrow = lane & 15, lgrp = lane >> 4;
    const int lr = lane >> 3, lc = lane & 7;

    f32x4 acc[4][2];
#pragma unroll
    for (int i = 0; i < 4; ++i)
#pragma unroll
        for (int j = 0; j < 2; ++j) acc[i][j] = (f32x4){0.f, 0.f, 0.f, 0.f};

    for (int kt = 0; kt < KDIM / 64; ++kt) {
        __syncthreads();
#pragma unroll
        for (int i = 0; i < 4; ++i) {
            int seg = wid * 4 + i;
            int r = seg * 8 + lr;
            size_t goff = (size_t)(bm * 128 + r) * KDIM + kt * 64 + (lc ^ (r & 7)) * 8;
            gld_lds16(smem + seg * 1024, xh + goff);
            gld_lds16(smem + 16384 + seg * 1024, xl + goff);
        }
#pragma unroll
        for (int i = 0; i < 2; ++i) {
            int seg = wid * 2 + i;
            int r = seg * 8 + lr;
            gld_lds16(smem + 32768 + seg * 1024,
                      Wt + (size_t)(bn * 64 + r) * KDIM + kt * 64 + (lc ^ (r & 7)) * 8);
        }
        __syncthreads();
#pragma unroll
        for (int ks = 0; ks < 2; ++ks) {
            bf16x8 bfr[2];
#pragma unroll
            for (int nf = 0; nf < 2; ++nf) {
                int rb = wn * 32 + nf * 16 + lrow;
                bfr[nf] = *(bf16x8_ma*)(smem + 32768 + ((rb * 128 + ks * 64 + lgrp * 16) ^ ((rb & 7) << 4)));
            }
#pragma unroll
            for (int mf = 0; mf < 4; ++mf) {
                int ra = wm * 64 + mf * 16 + lrow;
                int offa = (ra * 128 + ks * 64 + lgrp * 16) ^ ((ra & 7) << 4);
                bf16x8 ah = *(bf16x8_ma*)(smem + offa);
                bf16x8 al = *(bf16x8_ma*)(smem + 16384 + offa);
#pragma unroll
                for (int nf = 0; nf < 2; ++nf) {
                    acc[mf][nf] = __builtin_amdgcn_mfma_f32_16x16x32_bf16(ah, bfr[nf], acc[mf][nf], 0, 0, 0);
                    acc[mf][nf] = __builtin_amdgcn_mfma_f32_16x16x32_bf16(al, bfr[nf], acc[mf][nf], 0, 0, 0);
                }
            }
        }
    }

    const int g = bn >> 3;   // 0:Q 1:K 2:U 3:V
#pragma unroll
    for (int mf = 0; mf < 4; ++mf) {
#pragma unroll
        for (int nf = 0; nf < 2; ++nf) {
            int j0 = bn * 64 + wn * 32 + nf * 16 + lrow;
            int m0 = bm * 128 + wm * 64 + mf * 16 + lgrp * 4;
            if (g == 3) {
                // V -> fragment layout; r=0..3 are consecutive elems in one slot
                int dv = j0 - 1536;
                int bb = m0 >> 11, seq = m0 & (NSEQ - 1);
                size_t addr = (size_t)bb * 262144 + (size_t)(seq >> 6) * 8192
                    + (size_t)(((dv >> 4) * 2 + ((seq >> 5) & 1)) * 512)
                    + (((seq >> 3) & 3) * 16 + (dv & 15)) * 8 + (seq & 7);
                ushort4 h;
                h.x = f2bf(acc[mf][nf][0]); h.y = f2bf(acc[mf][nf][1]);
                h.z = f2bf(acc[mf][nf][2]); h.w = f2bf(acc[mf][nf][3]);
                *(ushort4*)&Vf[addr] = h;
            } else if (g == 1) {
                // K -> fragment layout
                int s = (j0 >> 6) & 7, d = j0 & 63;
#pragma unroll
                for (int r = 0; r < 4; ++r) {
                    int m = m0 + r;
                    int bb = m >> 11, seq = m & (NSEQ - 1);
                    size_t base = ((size_t)(bb * NS + s)) * (NSEQ * DH)
                        + (size_t)(seq >> 6) * 4096
                        + ((((seq >> 4) & 3) * 2 + (d >> 5)) * 64
                           + ((d & 31) >> 3) * 16 + (seq & 15)) * 8 + (d & 7);
                    Kf[base] = f2bf(acc[mf][nf][r]);
                }
            } else {
                int s = (j0 >> 6) & 7, d = j0 & 63;
#pragma unroll
                for (int r = 0; r < 4; ++r) {
                    int m = m0 + r;
                    int bb = m >> 11, seq = m & (NSEQ - 1);
                    size_t idx = (((size_t)(bb * NS + s)) * NSEQ + seq) * DH + d;
                    if (g == 2) RU[idx] = acc[mf][nf][r];
                    else        Qb[idx] = f2bf(acc[mf][nf][r]);
                }
            }
        }
    }
}

// ============ Kernel 2: barrier-free fragment-direct MFMA flash attention ============
// 4 fully independent waves/block (wave owns q = wid*16+lrow). K and V MFMA
// fragments loaded DIRECTLY from global in fragment order: each frag = one
// coalesced 1KB load/wave, L2-resident, XCD-swizzled. V(t) issued before
// QK/softmax (~400cy cover); K(t+1) a full iteration ahead. Only P uses LDS
// (2KB/wave, wave-local). ZERO barriers.
__global__ __launch_bounds__(256) void attn_mfma_k(
    const unsigned short* __restrict__ Qb, const unsigned short* __restrict__ Kfr,
    const unsigned short* __restrict__ Vfr, const float* __restrict__ RU,
    unsigned short* __restrict__ O1b)
{
    __shared__ __align__(16) char smem[8192];
    const int tid = threadIdx.x;
    const int gblk = blockIdx.x;
    const int orig = ((gblk & 7) << 6) + (gblk >> 3);   // XCD-contiguous remap
    const int qt = orig & 31, s = (orig >> 5) & 7, b = orig >> 8;
    const int wid = tid >> 6, lane = tid & 63;
    const int lrow = lane & 15, lgrp = lane >> 4;

    const unsigned short* Qg = Qb + (((size_t)(b * NS + s)) * NSEQ + qt * 64) * DH;
    const unsigned short* Kg = Kfr + ((size_t)(b * NS + s)) * (NSEQ * DH) + lane * 8;
    const unsigned short* Vg = Vfr + (size_t)b * 262144 + lane * 8;

    bf16x8 qf[2];
    {
        const unsigned short* qrow = Qg + (wid * 16 + lrow) * DH + lgrp * 8;
        qf[0] = *(const bf16x8_ma*)(qrow);
        qf[1] = *(const bf16x8_ma*)(qrow + 32);
    }

    char* sPw = smem + wid * 2048;
    const int pswz = (lrow & 7) << 4;

    bf16x8 kf[8], vf[16];
#define LOADK(T) do { const unsigned short* kq_ = Kg + (size_t)(T) * 4096;    \
        _Pragma("unroll")                                                     \
        for (int i_ = 0; i_ < 8; ++i_)                                        \
            kf[i_] = *(const bf16x8_ma*)(kq_ + i_ * 512); } while (0)
#define LOADV(T) do { const unsigned short* vq_ = Vg + (size_t)(T) * 8192;    \
        _Pragma("unroll")                                                     \
        for (int i_ = 0; i_ < 16; ++i_)                                       \
            vf[i_] = *(const bf16x8_ma*)(vq_ + i_ * 512); } while (0)

    f32x4 oacc[8];
#pragma unroll
    for (int df = 0; df < 8; ++df) oacc[df] = (f32x4){0.f, 0.f, 0.f, 0.f};
    float m_ = -1e30f, l_ = 0.f;
    f32x4 st[4];

    const int NT = NSEQ / 64;
    LOADK(0);

    for (int t = 0; t < NT; ++t) {
        // issue V(t): in flight during QK + softmax
        LOADV(t);

        // ---- S^T = K x Q^T : lane holds S[q=lrow][kv = nf*16 + lgrp*4 + r] ----
        __builtin_amdgcn_s_setprio(1);
#pragma unroll
        for (int nf = 0; nf < 4; ++nf) {
            st[nf] = (f32x4){0.f, 0.f, 0.f, 0.f};
            st[nf] = __builtin_amdgcn_mfma_f32_16x16x32_bf16(kf[nf * 2],     qf[0], st[nf], 0, 0, 0);
            st[nf] = __builtin_amdgcn_mfma_f32_16x16x32_bf16(kf[nf * 2 + 1], qf[1], st[nf], 0, 0, 0);
        }
        __builtin_amdgcn_s_setprio(0);

        // issue K(t+1) (kf just consumed)
        if (t + 1 < NT) LOADK(t + 1);

        // ---- online softmax, log2 domain, defer-rescale ----
        float mx = st[0][0];
#pragma unroll
        for (int nf = 0; nf < 4; ++nf)
#pragma unroll
            for (int r = 0; r < 4; ++r) mx = fmaxf(mx, st[nf][r]);
        mx = fmaxf(mx, __shfl_xor(mx, 16));
        mx = fmaxf(mx, __shfl_xor(mx, 32));
        if (__any(mx > m_ + 8.f)) {
            float mnew = fmaxf(m_, mx);
            float alpha = __builtin_exp2f(m_ - mnew);
#pragma unroll
            for (int df = 0; df < 8; ++df) oacc[df] = oacc[df] * alpha;
            l_ *= alpha;
            m_ = mnew;
        }
        float rs = 0.f;
#pragma unroll
        for (int nf = 0; nf < 4; ++nf)
#pragma unroll
            for (int r = 0; r < 4; ++r) {
                float p = __builtin_exp2f(st[nf][r] - m_);
                st[nf][r] = p;
                rs += p;
            }
        rs += __shfl_xor(rs, 16);
        rs += __shfl_xor(rs, 32);
        l_ += rs;

        // ---- P -> wave-local LDS roundtrip ----
#pragma unroll
        for (int nf = 0; nf < 4; ++nf) {
            uint2 w;
            w.x = cvt_pk_bf16(st[nf][0], st[nf][1]);
            w.y = cvt_pk_bf16(st[nf][2], st[nf][3]);
            *(uint2_ma*)(sPw + ((lrow * 128 + nf * 32 + lgrp * 8) ^ pswz)) = w;
        }

        // ---- O^T += V^T x P^T : vf regs (loads issued at top of iter) ----
        __builtin_amdgcn_s_setprio(1);
#pragma unroll
        for (int kkv = 0; kkv < 2; ++kkv) {
            bf16x8 pf = *(bf16x8_ma*)(sPw + ((lrow * 128 + kkv * 64 + lgrp * 16) ^ pswz));
#pragma unroll
            for (int df = 0; df < 8; ++df)
                oacc[df] = __builtin_amdgcn_mfma_f32_16x16x32_bf16(vf[df * 2 + kkv], pf, oacc[df], 0, 0, 0);
        }
        __builtin_amdgcn_s_setprio(0);
    }
#undef LOADK
#undef LOADV

    // ---- retrieval epilogue (register-only; u = x@Wc already has 0.125*log2e) ----
    {
        const int n = qt * 64 + wid * 16 + lrow;
        const float* ug = RU + ((((size_t)(b * NS + s)) * NSEQ) + n) * DH + lgrp * 4;
        float s0 = 0.f, s1 = 0.f;
#pragma unroll
        for (int df = 0; df < 4; ++df) {
            float4 u4 = *(const float4_ma*)(ug + df * 16);
            s0 += oacc[df][0] * u4.x + oacc[df][1] * u4.y + oacc[df][2] * u4.z + oacc[df][3] * u4.w;
            s1 += oacc[df + 4][0] * u4.x + oacc[df + 4][1] * u4.y + oacc[df + 4][2] * u4.z + oacc[df + 4][3] * u4.w;
        }
        s0 += __shfl_xor(s0, 16); s0 += __shfl_xor(s0, 32);
        s1 += __shfl_xor(s1, 16); s1 += __shfl_xor(s1, 32);
        float invl = 1.f / l_;
        float r0v = s0 * invl, r1v = s1 * invl;
        float mm = fmaxf(r0v, r1v);
        float e0 = __builtin_exp2f(r0v - mm), e1 = __builtin_exp2f(r1v - mm);
        float w = invl / (e0 + e1);
        float a0 = e0 * w, a1 = e1 * w;

        unsigned short* dst = O1b + ((size_t)(b * NSEQ + n)) * (NS * DH) + s * DH + lgrp * 4;
#pragma unroll
        for (int df = 0; df < 4; ++df) {
            float c0 = a0 * oacc[df][0] + a1 * oacc[df + 4][0];
            float c1 = a0 * oacc[df][1] + a1 * oacc[df + 4][1];
            float c2 = a0 * oacc[df][2] + a1 * oacc[df + 4][2];
            float c3 = a0 * oacc[df][3] + a1 * oacc[df + 4][3];
            uint2 o2;
            o2.x = cvt_pk_bf16(c0, c1);
            o2.y = cvt_pk_bf16(c2, c3);
            *(uint2_ma*)(dst + df * 16) = o2;
        }
    }
}

// ============ Kernel 3: output GEMM (bf16 MFMA, global_load_lds staging) ============
__global__ __launch_bounds__(256) void out_mfma_k(
    const unsigned short* __restrict__ A, const unsigned short* __restrict__ Bw,
    float* __restrict__ C)
{
    __shared__ __align__(16) char smem[24576];
    const int tid = threadIdx.x;
    const int bn = blockIdx.x, bm = blockIdx.y;
    const int wid = tid >> 6, lane = tid & 63;
    const int wm = wid >> 1, wn = wid & 1;
    const int lrow = lane & 15, lgrp = lane >> 4;
    const int lr = lane >> 3, lc = lane & 7;
    const int KD = NS * DH;   // 512

    f32x4 acc[4][2];
#pragma unroll
    for (int i = 0; i < 4; ++i)
#pragma unroll
        for (int j = 0; j < 2; ++j) acc[i][j] = (f32x4){0.f, 0.f, 0.f, 0.f};

    for (int kt = 0; kt < KD / 64; ++kt) {
        __syncthreads();
#pragma unroll
        for (int i = 0; i < 4; ++i) {
            int seg = wid * 4 + i;
            int r = seg * 8 + lr;
            gld_lds16(smem + seg * 1024,
                      A + (size_t)(bm * 128 + r) * KD + kt * 64 + (lc ^ (r & 7)) * 8);
        }
#pragma unroll
        for (int i = 0; i < 2; ++i) {
            int seg = wid * 2 + i;
            int r = seg * 8 + lr;
            gld_lds16(smem + 16384 + seg * 1024,
                      Bw + (size_t)(bn * 64 + r) * KD + kt * 64 + (lc ^ (r & 7)) * 8);
        }
        __syncthreads();
#pragma unroll
        for (int ks = 0; ks < 2; ++ks) {
            bf16x8 bfr[2];
#pragma unroll
            for (int nf = 0; nf < 2; ++nf) {
                int rb = wn * 32 + nf * 16 + lrow;
                bfr[nf] = *(bf16x8_ma*)(smem + 16384 + ((rb * 128 + ks * 64 + lgrp * 16) ^ ((rb & 7) << 4)));
            }
#pragma unroll
            for (int mf = 0; mf < 4; ++mf) {
                int ra = wm * 64 + mf * 16 + lrow;
                bf16x8 af = *(bf16x8_ma*)(smem + ((ra * 128 + ks * 64 + lgrp * 16) ^ ((ra & 7) << 4)));
#pragma unroll
                for (int nf = 0; nf < 2; ++nf)
                    acc[mf][nf] = __builtin_amdgcn_mfma_f32_16x16x32_bf16(af, bfr[nf], acc[mf][nf], 0, 0, 0);
            }
        }
    }

#pragma unroll
    for (int mf = 0; mf < 4; ++mf) {
#pragma unroll
        for (int nf = 0; nf < 2; ++nf) {
            int j0 = bn * 64 + wn * 32 + nf * 16 + lrow;
            int m0 = bm * 128 + wm * 64 + mf * 16 + lgrp * 4;
#pragma unroll
            for (int r = 0; r < 4; ++r)
                C[(size_t)(m0 + r) * KDIM + j0] = acc[mf][nf][r];
        }
    }
}

extern "C" void kernel_launch(void* const* d_in, const int* in_sizes, int n_in,
                              void* d_out, int out_size, void* d_ws, size_t ws_size,
                              hipStream_t stream)
{
    const float* x    = (const float*)d_in[0];
    const float* Wsq  = (const float*)d_in[1];
    const float* Wsk  = (const float*)d_in[2];
    const float* Wrv  = (const float*)d_in[3];
    const float* Wrq  = (const float*)d_in[4];
    const float* Wrk  = (const float*)d_in[5];
    const float* Wout = (const float*)d_in[6];
    float* out = (float*)d_out;

    // workspace layout (37.3 MB) — R9 layout; Kb slot holds fragmented K,
    // Vtb slot holds fragmented V.
    float* RU            = (float*)d_ws;                        // [2][8][2048][64] f32, 8 MB
    unsigned short* Wt   = (unsigned short*)(RU + (size_t)2 * NS * NSEQ * DH);  // [1664][1024], 3.25 MB
    unsigned short* Wot  = Wt + (size_t)1664 * KDIM;            // [1024][512], 1 MB
    unsigned short* Qb   = Wot + (size_t)KDIM * 512;            // [2][8][2048][64], 4 MB
    unsigned short* Kfr  = Qb + (size_t)2 * NS * NSEQ * DH;     // fragmented K, 4 MB
    unsigned short* Vfr  = Kfr + (size_t)2 * NS * NSEQ * DH;    // fragmented V, 1 MB
    unsigned short* xh   = Vfr + (size_t)2 * 128 * NSEQ;        // [4096][1024], 8 MB
    unsigned short* xl   = xh + (size_t)4096 * KDIM;            // 8 MB
    unsigned short* O1b  = xh;  // alias: xh dead after proj_mfma_k

    prep_w_k<<<544, 256, 0, stream>>>(Wsq, Wsk, Wrq, Wrv, Wout, Wt, Wot);
    prep_wc_k<<<dim3(8, 16), 256, 0, stream>>>(Wrq, Wrk, Wt);
    prep_x_k<<<2048, 256, 0, stream>>>(x, xh, xl);
    proj_mfma_k<<<dim3(26, 32), 256, 0, stream>>>(xh, xl, Wt, Qb, Kfr, RU, Vfr);
    attn_mfma_k<<<512, 256, 0, stream>>>(Qb, Kfr, Vfr, RU, O1b);
    out_mfma_k<<<dim3(16, 32), 256, 0, stream>>>(O1b, Wot, out);
}